// Round 5
// baseline (269.126 us; speedup 1.0000x reference)
//
#include <hip/hip_runtime.h>

typedef __attribute__((ext_vector_type(8))) short short8;
typedef __attribute__((ext_vector_type(4))) float f32x4;

#define DEVI __device__ __forceinline__

DEVI unsigned fbits(float f) { return __builtin_bit_cast(unsigned, f); }
DEVI unsigned short f2bf(float f) {
    unsigned u = __builtin_bit_cast(unsigned, f);
    u += 0x7fffu + ((u >> 16) & 1u);   // RNE
    return (unsigned short)(u >> 16);
}
// pack hi16(a)|hi16(b)<<16 (bf16 truncation, 1 instr)
DEVI unsigned pktrunc(float a, float b) {
    return __builtin_amdgcn_perm(fbits(b), fbits(a), 0x07060302u);
}
// async global->LDS, 16 B per lane; LDS dest = uniform base + lane*16
DEVI void async16(const unsigned short* g, unsigned short* l) {
    __builtin_amdgcn_global_load_lds(
        (const __attribute__((address_space(1))) void*)g,
        (__attribute__((address_space(3))) void*)l,
        16, 0, 0);
}

// ---------------------------------------------------------------- x f32 -> bf16
__global__ __launch_bounds__(256) void kcvt(const float* __restrict__ x,
                                            unsigned short* __restrict__ xb) {
    const int i = (blockIdx.x * 256 + threadIdx.x) * 4;
    const float4 v = *(const float4*)&x[i];
    uint2 pk;
    pk.x = (unsigned)f2bf(v.x) | ((unsigned)f2bf(v.y) << 16);
    pk.y = (unsigned)f2bf(v.z) | ((unsigned)f2bf(v.w) << 16);
    *(uint2*)&xb[i] = pk;
}

// ---------------------------------------------------------------- transpose + cvt
// w[768][2304] f32 -> wt[2304][768] bf16
__global__ void ktrans(const float* __restrict__ w,
                       unsigned short* __restrict__ wt) {
    __shared__ float t[32][33];
    const int tx = threadIdx.x, ty = threadIdx.y;   // 32 x 8
    const int n0 = blockIdx.x * 32, k0 = blockIdx.y * 32;
#pragma unroll
    for (int i = 0; i < 4; i++)
        t[ty + i * 8][tx] = w[(k0 + ty + i * 8) * 2304 + n0 + tx];
    __syncthreads();
#pragma unroll
    for (int i = 0; i < 4; i++)
        wt[(n0 + ty + i * 8) * 768 + k0 + tx] = f2bf(t[tx][ty + i * 8]);
}

// ---------------------------------------------------------------- QKV GEMM
// A = xb [8192][768] bf16, Bt = wt [2304][768] bf16; C = A*Bt^T + bias
// LDS in MFMA-fragment order: tile t holds rows [t*16,t*16+16) x 32 k,
// lane l's fragment at t*1024B + l*16B  ->  conflict-free b128 reads,
// async16 staging (one instr = one tile).
__global__ __launch_bounds__(256) void kgemm(
        const unsigned short* __restrict__ xb,
        const unsigned short* __restrict__ wt,
        const float* __restrict__ bias,
        unsigned short* __restrict__ q,
        unsigned short* __restrict__ k_,
        unsigned short* __restrict__ vt) {
    __shared__ __align__(16) unsigned short As[8 * 512];
    __shared__ __align__(16) unsigned short Bs[8 * 512];
    const int tid = threadIdx.x;
    const int w = tid >> 6, lane = tid & 63;
    const int wm = w >> 1, wn = w & 1;
    const int m0 = blockIdx.y * 128, n0 = blockIdx.x * 128;
    const int gr = lane & 15, gc = (lane >> 4) * 8;

    f32x4 acc[4][4] = {};

    for (int kk = 0; kk < 768; kk += 32) {
        __syncthreads();
#pragma unroll
        for (int j = 0; j < 2; j++) {
            const int t = w + j * 4;
            async16(&xb[(m0 + t * 16 + gr) * 768 + kk + gc], &As[t * 512]);
            async16(&wt[(n0 + t * 16 + gr) * 768 + kk + gc], &Bs[t * 512]);
        }
        __syncthreads();
        short8 af[4], bf[4];
#pragma unroll
        for (int mi = 0; mi < 4; mi++)
            af[mi] = *(const short8*)&As[(wm * 4 + mi) * 512 + lane * 8];
#pragma unroll
        for (int ni = 0; ni < 4; ni++)
            bf[ni] = *(const short8*)&Bs[(wn * 4 + ni) * 512 + lane * 8];
#pragma unroll
        for (int mi = 0; mi < 4; mi++)
#pragma unroll
            for (int ni = 0; ni < 4; ni++)
                acc[mi][ni] = __builtin_amdgcn_mfma_f32_16x16x32_bf16(
                    af[mi], bf[ni], acc[mi][ni], 0, 0, 0);
    }

    const int col0 = n0 + wn * 64;
    const int row0 = m0 + wm * 64;
#pragma unroll
    for (int mi = 0; mi < 4; mi++) {
#pragma unroll
        for (int ni = 0; ni < 4; ni++) {
            const int n_ = col0 + ni * 16 + (lane & 15);
            const float bv = bias[n_];
            const int which = n_ / 768;
            const int r7 = n_ % 768;
            const int h = r7 >> 6, d = r7 & 63;
#pragma unroll
            for (int r = 0; r < 4; r++) {
                const int m_ = row0 + mi * 16 + (lane >> 4) * 4 + r;
                const int bb = m_ >> 10, s = m_ & 1023;
                const int bh = bb * 12 + h;
                const unsigned short o = f2bf(acc[mi][ni][r] + bv);
                if (which == 0)      q[(bh * 1024 + s) * 64 + d] = o;
                else if (which == 1) k_[(bh * 1024 + s) * 64 + d] = o;
                else                 vt[(bh * 64 + d) * 1024 + s] = o;
            }
        }
    }
}

// ---------------------------------------------------------------- attention
// S^T = K*Q^T, softmax over keys, O^T = V^T*P^T.  K/V tiles staged via
// async16 in fragment order (tile (ti,ks) at (ti*2+ks)*1024B, lane*16B).
// P stored per-wave in fragment order via grp-remap.
#define SCL 0.18033688011112042f   // log2(e) / sqrt(64)

__global__ __launch_bounds__(256) void kattn(
        const unsigned short* __restrict__ q,
        const unsigned short* __restrict__ k_,
        const unsigned short* __restrict__ vt,
        float* __restrict__ out) {
    __shared__ __align__(16) unsigned short Ks[8 * 512];
    __shared__ __align__(16) unsigned short Vs[8 * 512];
    __shared__ __align__(16) unsigned short Ps[4][4 * 512];
    const int tid = threadIdx.x;
    const int w = tid >> 6, lane = tid & 63;
    const int bh = blockIdx.x;          // 96
    const int qt = blockIdx.y;          // 8
    const int bb = bh / 12, h = bh % 12;
    const unsigned short* qb = q + bh * 1024 * 64;
    const unsigned short* kb = k_ + bh * 1024 * 64;
    const unsigned short* vb = vt + bh * 64 * 1024;

    const int frow = lane & 15;         // q-row within 16-tile
    const int grp = lane >> 4;
    const int m0 = qt * 128 + w * 32;

    short8 qf[2][2];
#pragma unroll
    for (int mi = 0; mi < 2; mi++)
#pragma unroll
        for (int ks = 0; ks < 2; ks++)
            qf[mi][ks] = *(const short8*)&qb[(m0 + mi * 16 + frow) * 64 + ks * 32 + grp * 8];

    f32x4 oacc[2][4] = {};
    float rmax[2] = {-INFINITY, -INFINITY}, rsum[2] = {0.f, 0.f};

    for (int t0 = 0; t0 < 1024; t0 += 64) {
        __syncthreads();
#pragma unroll
        for (int j = 0; j < 2; j++) {
            const int t = w * 2 + j, ti = t >> 1, ks = t & 1;
            async16(&kb[(t0 + ti * 16 + frow) * 64 + ks * 32 + grp * 8], &Ks[t * 512]);
            async16(&vb[(ti * 16 + frow) * 1024 + t0 + ks * 32 + grp * 8], &Vs[t * 512]);
        }
        __syncthreads();

        // S^T = K * Q^T
        f32x4 sacc[4][2] = {};
#pragma unroll
        for (int ks = 0; ks < 2; ks++) {
            short8 kf[4];
#pragma unroll
            for (int ni = 0; ni < 4; ni++)
                kf[ni] = *(const short8*)&Ks[(ni * 2 + ks) * 512 + lane * 8];
#pragma unroll
            for (int ni = 0; ni < 4; ni++)
#pragma unroll
                for (int mi = 0; mi < 2; mi++)
                    sacc[ni][mi] = __builtin_amdgcn_mfma_f32_16x16x32_bf16(
                        kf[ni], qf[mi][ks], sacc[ni][mi], 0, 0, 0);
        }

        // online softmax; lane holds 16 keys for q-row mi*16+frow
#pragma unroll
        for (int mi = 0; mi < 2; mi++) {
            float mt = -INFINITY;
#pragma unroll
            for (int ni = 0; ni < 4; ni++)
#pragma unroll
                for (int r = 0; r < 4; r++) mt = fmaxf(mt, sacc[ni][mi][r]);
            mt = fmaxf(mt, __shfl_xor(mt, 16, 64));
            mt = fmaxf(mt, __shfl_xor(mt, 32, 64));
            const float mnew = fmaxf(rmax[mi], mt);
            const float alpha = exp2f((rmax[mi] - mnew) * SCL);
            rmax[mi] = mnew;
            const float mb = mnew * SCL;
            float ps = 0.f;
#pragma unroll
            for (int ni = 0; ni < 4; ni++)
#pragma unroll
                for (int r = 0; r < 4; r++) {
                    const float p = exp2f(sacc[ni][mi][r] * SCL - mb);
                    sacc[ni][mi][r] = p;
                    ps += p;
                }
            ps += __shfl_xor(ps, 16, 64);
            ps += __shfl_xor(ps, 32, 64);
            rsum[mi] = rsum[mi] * alpha + ps;
#pragma unroll
            for (int di = 0; di < 4; di++) oacc[mi][di] *= alpha;
            // P[q][key] -> fragment-order tiles (mi, ks=ni>>1)
#pragma unroll
            for (int ni = 0; ni < 4; ni++) {
                uint2 pk;
                pk.x = pktrunc(sacc[ni][mi][0], sacc[ni][mi][1]);
                pk.y = pktrunc(sacc[ni][mi][2], sacc[ni][mi][3]);
                const int dlane = frow + (((ni << 1) + (grp >> 1)) & 3) * 16;
                *(uint2*)&Ps[w][(mi * 2 + (ni >> 1)) * 512 + dlane * 8 + (grp & 1) * 4] = pk;
            }
        }

        // O^T += V^T * P^T
#pragma unroll
        for (int ks = 0; ks < 2; ks++) {
            short8 vf[4], pf[2];
#pragma unroll
            for (int di = 0; di < 4; di++)
                vf[di] = *(const short8*)&Vs[(di * 2 + ks) * 512 + lane * 8];
#pragma unroll
            for (int mi = 0; mi < 2; mi++)
                pf[mi] = *(const short8*)&Ps[w][(mi * 2 + ks) * 512 + lane * 8];
#pragma unroll
            for (int mi = 0; mi < 2; mi++)
#pragma unroll
                for (int di = 0; di < 4; di++)
                    oacc[mi][di] = __builtin_amdgcn_mfma_f32_16x16x32_bf16(
                        vf[di], pf[mi], oacc[mi][di], 0, 0, 0);
        }
    }

    // epilogue: O^T/l -> out[b][s][h*64+d], float4 stores
#pragma unroll
    for (int mi = 0; mi < 2; mi++) {
        const float inv = 1.0f / rsum[mi];
        const int s = m0 + mi * 16 + frow;
#pragma unroll
        for (int di = 0; di < 4; di++) {
            f32x4 o = oacc[mi][di] * inv;
            const int d0 = di * 16 + grp * 4;
            *(f32x4*)&out[(bb * 1024 + s) * 768 + h * 64 + d0] = o;
        }
    }
}

// ---------------------------------------------------------------- residual + LN (f32)
__global__ __launch_bounds__(256) void kln(
        const float* __restrict__ x,
        const float* __restrict__ gamma,
        const float* __restrict__ beta,
        float* __restrict__ out) {
    __shared__ float red[8];
    const int row = blockIdx.x;
    const int tid = threadIdx.x;
    const float* xr = x + row * 768;
    float* orow = out + row * 768;
    float y[3], sum = 0.f, sumsq = 0.f;
#pragma unroll
    for (int i = 0; i < 3; i++) {
        const int e = tid + i * 256;
        const float v = xr[e] + orow[e];
        y[i] = v; sum += v; sumsq += v * v;
    }
#pragma unroll
    for (int o = 1; o < 64; o <<= 1) {
        sum += __shfl_xor(sum, o, 64);
        sumsq += __shfl_xor(sumsq, o, 64);
    }
    const int w = tid >> 6, lane = tid & 63;
    if (lane == 0) { red[w] = sum; red[4 + w] = sumsq; }
    __syncthreads();
    sum = red[0] + red[1] + red[2] + red[3];
    sumsq = red[4] + red[5] + red[6] + red[7];
    const float mean = sum * (1.0f / 768.0f);
    const float var = sumsq * (1.0f / 768.0f) - mean * mean;
    const float rs = rsqrtf(var + 1e-5f);
#pragma unroll
    for (int i = 0; i < 3; i++) {
        const int e = tid + i * 256;
        orow[e] = (y[i] - mean) * rs * gamma[e] + beta[e];
    }
}

// ---------------------------------------------------------------- launch
extern "C" void kernel_launch(void* const* d_in, const int* in_sizes, int n_in,
                              void* d_out, int out_size, void* d_ws, size_t ws_size,
                              hipStream_t stream) {
    (void)in_sizes; (void)n_in; (void)out_size; (void)ws_size;
    const float* x     = (const float*)d_in[0];
    const float* wqkv  = (const float*)d_in[1];
    const float* bqkv  = (const float*)d_in[2];
    const float* gamma = (const float*)d_in[3];
    const float* beta  = (const float*)d_in[4];
    float* out = (float*)d_out;
    unsigned short* ws = (unsigned short*)d_ws;

    unsigned short* wt = ws;                       // 2304*768   bf16
    unsigned short* xb = wt + 2304 * 768;          // 8192*768   bf16
    unsigned short* q  = xb + 8192 * 768;          // 96*1024*64 bf16
    unsigned short* k  = q + 96 * 1024 * 64;       // 96*1024*64 bf16
    unsigned short* vt = k + 96 * 1024 * 64;       // 96*64*1024 bf16
    // total ws use: ~53.9 MB

    kcvt<<<6144, 256, 0, stream>>>(x, xb);
    ktrans<<<dim3(72, 24), dim3(32, 8), 0, stream>>>(wqkv, wt);
    kgemm<<<dim3(18, 64), 256, 0, stream>>>(xb, wt, bqkv, q, k, vt);
    kattn<<<dim3(96, 8), 256, 0, stream>>>(q, k, vt, out);
    kln<<<8192, 256, 0, stream>>>(x, gamma, beta, out);
}

// Round 6
// 248.932 us; speedup vs baseline: 1.0811x; 1.0811x over previous
//
#include <hip/hip_runtime.h>

typedef __attribute__((ext_vector_type(8))) short short8;
typedef __attribute__((ext_vector_type(4))) float f32x4;

#define DEVI __device__ __forceinline__

DEVI unsigned fbits(float f) { return __builtin_bit_cast(unsigned, f); }
DEVI unsigned short f2bf(float f) {
    unsigned u = __builtin_bit_cast(unsigned, f);
    u += 0x7fffu + ((u >> 16) & 1u);   // RNE
    return (unsigned short)(u >> 16);
}
// pack hi16(a)|hi16(b)<<16 (bf16 truncation, 1 instr)
DEVI unsigned pktrunc(float a, float b) {
    return __builtin_amdgcn_perm(fbits(b), fbits(a), 0x07060302u);
}
// async global->LDS, 16 B per lane; LDS dest = uniform base + lane*16
DEVI void async16(const unsigned short* g, unsigned short* l) {
    __builtin_amdgcn_global_load_lds(
        (const __attribute__((address_space(1))) void*)g,
        (__attribute__((address_space(3))) void*)l,
        16, 0, 0);
}
// manual pipeline control: raw barrier + fine-grained vmcnt, both with
// compiler memory fences so nothing is reordered across them
#define BAR()    asm volatile("s_barrier" ::: "memory")
#define WAITV4() asm volatile("s_waitcnt vmcnt(4)" ::: "memory")
#define WAITV0() asm volatile("s_waitcnt vmcnt(0)" ::: "memory")

// ---------------------------------------------------------------- x f32 -> bf16
__global__ __launch_bounds__(256) void kcvt(const float* __restrict__ x,
                                            unsigned short* __restrict__ xb) {
    const int i = (blockIdx.x * 256 + threadIdx.x) * 4;
    const float4 v = *(const float4*)&x[i];
    uint2 pk;
    pk.x = (unsigned)f2bf(v.x) | ((unsigned)f2bf(v.y) << 16);
    pk.y = (unsigned)f2bf(v.z) | ((unsigned)f2bf(v.w) << 16);
    *(uint2*)&xb[i] = pk;
}

// ---------------------------------------------------------------- transpose + cvt
// w[768][2304] f32 -> wt[2304][768] bf16
__global__ void ktrans(const float* __restrict__ w,
                       unsigned short* __restrict__ wt) {
    __shared__ float t[32][33];
    const int tx = threadIdx.x, ty = threadIdx.y;   // 32 x 8
    const int n0 = blockIdx.x * 32, k0 = blockIdx.y * 32;
#pragma unroll
    for (int i = 0; i < 4; i++)
        t[ty + i * 8][tx] = w[(k0 + ty + i * 8) * 2304 + n0 + tx];
    __syncthreads();
#pragma unroll
    for (int i = 0; i < 4; i++)
        wt[(n0 + ty + i * 8) * 768 + k0 + tx] = f2bf(t[tx][ty + i * 8]);
}

// ---------------------------------------------------------------- QKV GEMM
// A = xb [8192][768] bf16, Bt = wt [2304][768] bf16; C = A*Bt^T + bias
// Fragment-order LDS tiles (conflict-free b128 reads), async16 staging,
// 3-buffer depth-2 software pipeline with manual vmcnt/s_barrier.
__global__ __launch_bounds__(256) void kgemm(
        const unsigned short* __restrict__ xb,
        const unsigned short* __restrict__ wt,
        const float* __restrict__ bias,
        unsigned short* __restrict__ q,
        unsigned short* __restrict__ k_,
        unsigned short* __restrict__ vt) {
    __shared__ __align__(16) unsigned short As[3][8 * 512];
    __shared__ __align__(16) unsigned short Bs[3][8 * 512];
    const int tid = threadIdx.x;
    const int w = tid >> 6, lane = tid & 63;
    const int wm = w >> 1, wn = w & 1;
    const int m0 = blockIdx.y * 128, n0 = blockIdx.x * 128;
    const int gr = lane & 15, gc = (lane >> 4) * 8;

    f32x4 acc[4][4] = {};

    // issue one K-tile pair (4 DMA instructions per wave)
    auto issue = [&](int kk, int b) {
#pragma unroll
        for (int j = 0; j < 2; j++) {
            const int t = w + j * 4;
            async16(&xb[(m0 + t * 16 + gr) * 768 + kk + gc], &As[b][t * 512]);
            async16(&wt[(n0 + t * 16 + gr) * 768 + kk + gc], &Bs[b][t * 512]);
        }
    };

    issue(0, 0);
    issue(32, 1);

    for (int it = 0; it < 24; it++) {
        const int cur = it % 3;
        if (it < 23) { WAITV4(); } else { WAITV0(); }   // tile `it` resident
        BAR();
        if (it + 2 < 24) issue((it + 2) * 32, (it + 2) % 3);

        short8 af[4], bf[4];
#pragma unroll
        for (int mi = 0; mi < 4; mi++)
            af[mi] = *(const short8*)&As[cur][(wm * 4 + mi) * 512 + lane * 8];
#pragma unroll
        for (int ni = 0; ni < 4; ni++)
            bf[ni] = *(const short8*)&Bs[cur][(wn * 4 + ni) * 512 + lane * 8];
#pragma unroll
        for (int mi = 0; mi < 4; mi++)
#pragma unroll
            for (int ni = 0; ni < 4; ni++)
                acc[mi][ni] = __builtin_amdgcn_mfma_f32_16x16x32_bf16(
                    af[mi], bf[ni], acc[mi][ni], 0, 0, 0);
    }

    const int col0 = n0 + wn * 64;
    const int row0 = m0 + wm * 64;
#pragma unroll
    for (int mi = 0; mi < 4; mi++) {
#pragma unroll
        for (int ni = 0; ni < 4; ni++) {
            const int n_ = col0 + ni * 16 + (lane & 15);
            const float bv = bias[n_];
            const int which = n_ / 768;
            const int r7 = n_ % 768;
            const int h = r7 >> 6, d = r7 & 63;
#pragma unroll
            for (int r = 0; r < 4; r++) {
                const int m_ = row0 + mi * 16 + (lane >> 4) * 4 + r;
                const int bb = m_ >> 10, s = m_ & 1023;
                const int bh = bb * 12 + h;
                const unsigned short o = f2bf(acc[mi][ni][r] + bv);
                if (which == 0)      q[(bh * 1024 + s) * 64 + d] = o;
                else if (which == 1) k_[(bh * 1024 + s) * 64 + d] = o;
                else                 vt[(bh * 64 + d) * 1024 + s] = o;
            }
        }
    }
}

// ---------------------------------------------------------------- attention
// S^T = K*Q^T, softmax over keys, O^T = V^T*P^T.  Fragment-order async
// K/V staging, 2-buffer depth-1 pipeline w/ manual vmcnt/s_barrier.
#define SCL 0.18033688011112042f   // log2(e) / sqrt(64)

__global__ __launch_bounds__(256) void kattn(
        const unsigned short* __restrict__ q,
        const unsigned short* __restrict__ k_,
        const unsigned short* __restrict__ vt,
        float* __restrict__ out) {
    __shared__ __align__(16) unsigned short Ks[2][8 * 512];
    __shared__ __align__(16) unsigned short Vs[2][8 * 512];
    __shared__ __align__(16) unsigned short Ps[4][4 * 512];
    const int tid = threadIdx.x;
    const int w = tid >> 6, lane = tid & 63;
    const int bh = blockIdx.x;          // 96
    const int qt = blockIdx.y;          // 8
    const int bb = bh / 12, h = bh % 12;
    const unsigned short* qb = q + bh * 1024 * 64;
    const unsigned short* kb = k_ + bh * 1024 * 64;
    const unsigned short* vb = vt + bh * 64 * 1024;

    const int frow = lane & 15;         // q-row within 16-tile
    const int grp = lane >> 4;
    const int m0 = qt * 128 + w * 32;

    auto issue = [&](int t0, int b) {
#pragma unroll
        for (int j = 0; j < 2; j++) {
            const int t = w * 2 + j, ti = t >> 1, ks = t & 1;
            async16(&kb[(t0 + ti * 16 + frow) * 64 + ks * 32 + grp * 8], &Ks[b][t * 512]);
            async16(&vb[(ti * 16 + frow) * 1024 + t0 + ks * 32 + grp * 8], &Vs[b][t * 512]);
        }
    };

    short8 qf[2][2];
#pragma unroll
    for (int mi = 0; mi < 2; mi++)
#pragma unroll
        for (int ks = 0; ks < 2; ks++)
            qf[mi][ks] = *(const short8*)&qb[(m0 + mi * 16 + frow) * 64 + ks * 32 + grp * 8];

    issue(0, 0);

    f32x4 oacc[2][4] = {};
    float rmax[2] = {-INFINITY, -INFINITY}, rsum[2] = {0.f, 0.f};

    for (int tt = 0; tt < 16; tt++) {
        const int cur = tt & 1;
        WAITV0();                       // tile tt resident (overlapped w/ prev compute)
        BAR();
        if (tt + 1 < 16) issue((tt + 1) * 64, cur ^ 1);

        // S^T = K * Q^T
        f32x4 sacc[4][2] = {};
#pragma unroll
        for (int ks = 0; ks < 2; ks++) {
            short8 kf[4];
#pragma unroll
            for (int ni = 0; ni < 4; ni++)
                kf[ni] = *(const short8*)&Ks[cur][(ni * 2 + ks) * 512 + lane * 8];
#pragma unroll
            for (int ni = 0; ni < 4; ni++)
#pragma unroll
                for (int mi = 0; mi < 2; mi++)
                    sacc[ni][mi] = __builtin_amdgcn_mfma_f32_16x16x32_bf16(
                        kf[ni], qf[mi][ks], sacc[ni][mi], 0, 0, 0);
        }

        // online softmax; lane holds 16 keys for q-row mi*16+frow
#pragma unroll
        for (int mi = 0; mi < 2; mi++) {
            float mt = -INFINITY;
#pragma unroll
            for (int ni = 0; ni < 4; ni++)
#pragma unroll
                for (int r = 0; r < 4; r++) mt = fmaxf(mt, sacc[ni][mi][r]);
            mt = fmaxf(mt, __shfl_xor(mt, 16, 64));
            mt = fmaxf(mt, __shfl_xor(mt, 32, 64));
            const float mnew = fmaxf(rmax[mi], mt);
            const float alpha = exp2f((rmax[mi] - mnew) * SCL);
            rmax[mi] = mnew;
            const float mb = mnew * SCL;
            float ps = 0.f;
#pragma unroll
            for (int ni = 0; ni < 4; ni++)
#pragma unroll
                for (int r = 0; r < 4; r++) {
                    const float p = exp2f(sacc[ni][mi][r] * SCL - mb);
                    sacc[ni][mi][r] = p;
                    ps += p;
                }
            ps += __shfl_xor(ps, 16, 64);
            ps += __shfl_xor(ps, 32, 64);
            rsum[mi] = rsum[mi] * alpha + ps;
#pragma unroll
            for (int di = 0; di < 4; di++) oacc[mi][di] *= alpha;
            // P[q][key] -> fragment-order tiles (mi, ks=ni>>1); same-wave
            // ds_write -> ds_read (in-order, no barrier needed)
#pragma unroll
            for (int ni = 0; ni < 4; ni++) {
                uint2 pk;
                pk.x = pktrunc(sacc[ni][mi][0], sacc[ni][mi][1]);
                pk.y = pktrunc(sacc[ni][mi][2], sacc[ni][mi][3]);
                const int dlane = frow + (((ni << 1) + (grp >> 1)) & 3) * 16;
                *(uint2*)&Ps[w][(mi * 2 + (ni >> 1)) * 512 + dlane * 8 + (grp & 1) * 4] = pk;
            }
        }

        // O^T += V^T * P^T
#pragma unroll
        for (int ks = 0; ks < 2; ks++) {
            short8 vf[4], pf[2];
#pragma unroll
            for (int di = 0; di < 4; di++)
                vf[di] = *(const short8*)&Vs[cur][(di * 2 + ks) * 512 + lane * 8];
#pragma unroll
            for (int mi = 0; mi < 2; mi++)
                pf[mi] = *(const short8*)&Ps[w][(mi * 2 + ks) * 512 + lane * 8];
#pragma unroll
            for (int mi = 0; mi < 2; mi++)
#pragma unroll
                for (int di = 0; di < 4; di++)
                    oacc[mi][di] = __builtin_amdgcn_mfma_f32_16x16x32_bf16(
                        vf[di], pf[mi], oacc[mi][di], 0, 0, 0);
        }
    }

    // epilogue: O^T/l -> out[b][s][h*64+d], float4 stores
#pragma unroll
    for (int mi = 0; mi < 2; mi++) {
        const float inv = 1.0f / rsum[mi];
        const int s = m0 + mi * 16 + frow;
#pragma unroll
        for (int di = 0; di < 4; di++) {
            f32x4 o = oacc[mi][di] * inv;
            const int d0 = di * 16 + grp * 4;
            *(f32x4*)&out[(bb * 1024 + s) * 768 + h * 64 + d0] = o;
        }
    }
}

// ---------------------------------------------------------------- residual + LN (f32)
__global__ __launch_bounds__(256) void kln(
        const float* __restrict__ x,
        const float* __restrict__ gamma,
        const float* __restrict__ beta,
        float* __restrict__ out) {
    __shared__ float red[8];
    const int row = blockIdx.x;
    const int tid = threadIdx.x;
    const float* xr = x + row * 768;
    float* orow = out + row * 768;
    float y[3], sum = 0.f, sumsq = 0.f;
#pragma unroll
    for (int i = 0; i < 3; i++) {
        const int e = tid + i * 256;
        const float v = xr[e] + orow[e];
        y[i] = v; sum += v; sumsq += v * v;
    }
#pragma unroll
    for (int o = 1; o < 64; o <<= 1) {
        sum += __shfl_xor(sum, o, 64);
        sumsq += __shfl_xor(sumsq, o, 64);
    }
    const int w = tid >> 6, lane = tid & 63;
    if (lane == 0) { red[w] = sum; red[4 + w] = sumsq; }
    __syncthreads();
    sum = red[0] + red[1] + red[2] + red[3];
    sumsq = red[4] + red[5] + red[6] + red[7];
    const float mean = sum * (1.0f / 768.0f);
    const float var = sumsq * (1.0f / 768.0f) - mean * mean;
    const float rs = rsqrtf(var + 1e-5f);
#pragma unroll
    for (int i = 0; i < 3; i++) {
        const int e = tid + i * 256;
        orow[e] = (y[i] - mean) * rs * gamma[e] + beta[e];
    }
}

// ---------------------------------------------------------------- launch
extern "C" void kernel_launch(void* const* d_in, const int* in_sizes, int n_in,
                              void* d_out, int out_size, void* d_ws, size_t ws_size,
                              hipStream_t stream) {
    (void)in_sizes; (void)n_in; (void)out_size; (void)ws_size;
    const float* x     = (const float*)d_in[0];
    const float* wqkv  = (const float*)d_in[1];
    const float* bqkv  = (const float*)d_in[2];
    const float* gamma = (const float*)d_in[3];
    const float* beta  = (const float*)d_in[4];
    float* out = (float*)d_out;
    unsigned short* ws = (unsigned short*)d_ws;

    unsigned short* wt = ws;                       // 2304*768   bf16
    unsigned short* xb = wt + 2304 * 768;          // 8192*768   bf16
    unsigned short* q  = xb + 8192 * 768;          // 96*1024*64 bf16
    unsigned short* k  = q + 96 * 1024 * 64;       // 96*1024*64 bf16
    unsigned short* vt = k + 96 * 1024 * 64;       // 96*64*1024 bf16

    kcvt<<<6144, 256, 0, stream>>>(x, xb);
    ktrans<<<dim3(72, 24), dim3(32, 8), 0, stream>>>(wqkv, wt);
    kgemm<<<dim3(18, 64), 256, 0, stream>>>(xb, wt, bqkv, q, k, vt);
    kattn<<<dim3(96, 8), 256, 0, stream>>>(q, k, vt, out);
    kln<<<8192, 256, 0, stream>>>(x, gamma, beta, out);
}